// Round 5
// baseline (635.818 us; speedup 1.0000x reference)
//
#include <hip/hip_runtime.h>
#include <hip/hip_bf16.h>

#define NH 12
#define HD 64
#define NB 4
#define SEQ 2048
#define NP 768
#define LOG2E 1.44269504f
#define MASK_L2 14426.9504f   // 10000 * log2(e)

typedef __bf16 bf16x8 __attribute__((ext_vector_type(8)));
typedef __bf16 bf16x4 __attribute__((ext_vector_type(4)));
typedef short s16x4 __attribute__((ext_vector_type(4)));
typedef float f32x4 __attribute__((ext_vector_type(4)));

static __device__ __forceinline__ bf16x8 load_bf16x8(const __bf16* p) {
    return *reinterpret_cast<const bf16x8*>(p);
}

// exp2 via the raw hardware transcendental (v_exp_f32); avoids the glibc
// __exp2f macro collision. Device pass verified clean in round 4.
static __device__ __forceinline__ float hw_exp2(float x) {
    return __builtin_amdgcn_exp2f(x);
}

// 16x16x16 bf16 MFMA (K=16): B-operand layout k=4g+j == C-layout rows 4g+r,
// so P^T coming out of the S^T MFMA feeds PV with zero data movement.
// NOTE: the __HIP_DEVICE_COMPILE__ guard is load-bearing — in the host pass
// __has_builtin() is false for amdgcn builtins, which previously tripped a
// #error while parsing this function for host. Host never executes this.
static __device__ __forceinline__ f32x4 mfma_pv(s16x4 a, s16x4 b, f32x4 c) {
#if !defined(__HIP_DEVICE_COMPILE__)
    (void)a; (void)b;
    return c;
#elif __has_builtin(__builtin_amdgcn_mfma_f32_16x16x16_bf16)
    return __builtin_amdgcn_mfma_f32_16x16x16_bf16(
        __builtin_bit_cast(bf16x4, a), __builtin_bit_cast(bf16x4, b), c, 0, 0, 0);
#else
    return __builtin_amdgcn_mfma_f32_16x16x16bf16_1k(a, b, c, 0, 0, 0);
#endif
}

// ---------------------------------------------------------------------------
// Kernel 0: W (64,768) fp32 -> Wt (768,64) bf16, scale 0.125*log2e folded for Q.
// LDS tile transpose, fully coalesced both sides. grid (12, 3).
// ---------------------------------------------------------------------------
__global__ __launch_bounds__(256) void wt_kernel(
    const float* __restrict__ Wq, const float* __restrict__ Wk,
    const float* __restrict__ Wv, __bf16* __restrict__ Wt)
{
    __shared__ float tile[64][69];
    const int by = blockIdx.y;
    const float* W = by == 0 ? Wq : (by == 1 ? Wk : Wv);
    const float scale = (by == 0) ? 0.125f * LOG2E : 1.0f;
    const int p0 = blockIdx.x * 64;
    const int tl = threadIdx.x & 63;
    const int tq = threadIdx.x >> 6;
    #pragma unroll
    for (int i = 0; i < 16; ++i) {
        const int d = tq + 4 * i;
        tile[tl][d] = W[(size_t)d * NP + p0 + tl];
    }
    __syncthreads();
    #pragma unroll
    for (int i = 0; i < 16; ++i) {
        const int pl = tq + 4 * i;
        Wt[((size_t)by * NP + p0 + pl) * HD + tl] = (__bf16)(tile[pl][tl] * scale);
    }
}

// ---------------------------------------------------------------------------
// Kernel 1 v4: QKV projection with transposed bf16 weights: both MFMA operands
// are contiguous 16B loads. Wave = 16 rows, loops 24 p-tiles. grid = 768.
// Q carries 0.125*log2e (folded in Wt/bias) so flash uses exp2 directly.
// ---------------------------------------------------------------------------
__global__ __launch_bounds__(256) void qkv_kernel(
    const float* __restrict__ hidden, const __bf16* __restrict__ Wt,
    const float* __restrict__ bq, const float* __restrict__ bk,
    const float* __restrict__ bv,
    __bf16* __restrict__ Qw, __bf16* __restrict__ Kw, __bf16* __restrict__ Vtw)
{
    const int lane = threadIdx.x & 63;
    const int w    = threadIdx.x >> 6;
    const int g    = lane >> 4;
    const int n    = lane & 15;

    const int bid    = blockIdx.x;
    const int pi     = bid >> 8;
    const int pchunk = (bid >> 7) & 1;
    const int rblk   = bid & 127;
    const int row0   = rblk * 64 + w * 16;
    const int b_     = row0 >> 11;
    const int t0     = row0 & (SEQ - 1);

    const float* bias = pi == 0 ? bq : (pi == 1 ? bk : bv);
    const float qs = (pi == 0) ? 0.125f * LOG2E : 1.0f;
    const __bf16* Wtp = Wt + (size_t)pi * NP * HD;

    // A fragment: A[m=n][k=8g+j], rows row0+n
    const float* hrow = hidden + (size_t)(row0 + n) * HD + 8 * g;
    f32x4 h0 = *(const f32x4*)(hrow);
    f32x4 h1 = *(const f32x4*)(hrow + 4);
    f32x4 h2 = *(const f32x4*)(hrow + 32);
    f32x4 h3 = *(const f32x4*)(hrow + 36);
    bf16x8 a0, a1;
    #pragma unroll
    for (int j = 0; j < 4; ++j) {
        a0[j]     = (__bf16)h0[j];
        a0[j + 4] = (__bf16)h1[j];
        a1[j]     = (__bf16)h2[j];
        a1[j + 4] = (__bf16)h3[j];
    }

    for (int pt = pchunk * 24; pt < pchunk * 24 + 24; ++pt) {
        const int pbase = pt * 16;
        // B[k=8g+j][n] = W[k][pbase+n] = Wt[pbase+n][8g+j]: contiguous 16B
        const __bf16* wp = Wtp + (size_t)(pbase + n) * HD + 8 * g;
        bf16x8 w0 = load_bf16x8(wp);
        bf16x8 w1 = load_bf16x8(wp + 32);

        f32x4 acc = {0.f, 0.f, 0.f, 0.f};
        acc = __builtin_amdgcn_mfma_f32_16x16x32_bf16(a0, w0, acc, 0, 0, 0);
        acc = __builtin_amdgcn_mfma_f32_16x16x32_bf16(a1, w1, acc, 0, 0, 0);

        const float bb  = bias[pbase + n] * qs;
        const int h     = pbase >> 6;
        const int dbase = pbase & 63;
        const int bh    = b_ * NH + h;

        if (pi < 2) {
            __bf16* dst = (pi == 0 ? Qw : Kw) + ((size_t)bh * SEQ) * HD + dbase + n;
            #pragma unroll
            for (int r = 0; r < 4; ++r)
                dst[(size_t)(t0 + 4 * g + r) * HD] = (__bf16)(acc[r] + bb);
        } else {
            __bf16* dst = Vtw + ((size_t)bh * HD + dbase + n) * SEQ;
            #pragma unroll
            for (int r = 0; r < 4; ++r)
                dst[t0 + 4 * g + r] = (__bf16)(acc[r] + bb);
        }
    }
}

// ---------------------------------------------------------------------------
// Kernel 2 v4: flash attention via S^T. Per 32-key iter: 4 S-MFMAs (16x16x32,
// A=K B=Q -> S^T in C-layout), exp2 (mask folded), per-lane partial row sums
// (no cross-lane ops), P^T fed straight into 8 PV-MFMAs (16x16x16, A=V^T).
// No LDS / no barriers in the loop. XCD swizzle co-locates each head's
// q-blocks on one XCD for K/V L2 reuse.
// ---------------------------------------------------------------------------
__global__ __launch_bounds__(256, 4) void flash_attn_kernel(
    const __bf16* __restrict__ Qw, const __bf16* __restrict__ Kw,
    const __bf16* __restrict__ Vtw, const float* __restrict__ amask,
    float* __restrict__ out)
{
    __shared__ float et[4][16][68];

    const int lane = threadIdx.x & 63;
    const int w    = threadIdx.x >> 6;
    const int g    = lane >> 4;
    const int n    = lane & 15;

    const int bid   = blockIdx.x;
    const int xcd   = bid & 7;
    const int slot  = bid >> 3;           // 0..191
    const int bh    = xcd * 6 + (slot >> 5);
    const int qtile = slot & 31;
    const int b_    = bh / NH;
    const int h     = bh % NH;
    const int q0    = qtile * 64 + w * 16;

    // Q as B-operand: B[k=8g+j][q=n] = Q[q0+n][8g+j] (same load as A-frag)
    const __bf16* qptr = Qw + ((size_t)bh * SEQ + q0 + n) * HD + 8 * g;
    const bf16x8 qa0 = load_bf16x8(qptr);
    const bf16x8 qa1 = load_bf16x8(qptr + 32);

    const __bf16* Kbh = Kw  + (size_t)bh * SEQ * HD;
    const __bf16* Vbh = Vtw + (size_t)bh * HD * SEQ;
    const float* mptr = amask + (size_t)b_ * SEQ;

    // O^T accumulators: o[dt] holds O^T[d=16dt+4g+r][q=n]
    f32x4 o0 = {0,0,0,0}, o1 = {0,0,0,0}, o2 = {0,0,0,0}, o3 = {0,0,0,0};
    float lsl = 0.f;   // per-lane partial sum over this lane's keys, q=n

    for (int kb = 0; kb < SEQ; kb += 32) {
        // K as A-operand: A[m=key=n][k=8g+j], contiguous 16B
        const __bf16* kp = Kbh + (size_t)(kb + n) * HD + 8 * g;
        bf16x8 ka0 = load_bf16x8(kp);
        bf16x8 ka1 = load_bf16x8(kp + 32);
        bf16x8 kb0 = load_bf16x8(kp + 16 * HD);
        bf16x8 kb1 = load_bf16x8(kp + 16 * HD + 32);

        // V^T as PV A-operand: A[m=d_local=n][k=4g+j] = Vt[16dt+n][kb+4g+j]
        const __bf16* vp = Vbh + (size_t)n * SEQ + kb + 4 * g;
        s16x4 va0 = *(const s16x4*)(vp);
        s16x4 va1 = *(const s16x4*)(vp + 16 * SEQ);
        s16x4 va2 = *(const s16x4*)(vp + 32 * SEQ);
        s16x4 va3 = *(const s16x4*)(vp + 48 * SEQ);
        s16x4 vb0 = *(const s16x4*)(vp + 16);
        s16x4 vb1 = *(const s16x4*)(vp + 16 * SEQ + 16);
        s16x4 vb2 = *(const s16x4*)(vp + 32 * SEQ + 16);
        s16x4 vb3 = *(const s16x4*)(vp + 48 * SEQ + 16);

        f32x4 ma = *(const f32x4*)(mptr + kb + 4 * g);
        f32x4 mb = *(const f32x4*)(mptr + kb + 16 + 4 * g);

        // S^T[key=4g+r][q=n], already in log2 domain (scale folded into Q)
        f32x4 sa = {0,0,0,0}, sb = {0,0,0,0};
        sa = __builtin_amdgcn_mfma_f32_16x16x32_bf16(ka0, qa0, sa, 0, 0, 0);
        sa = __builtin_amdgcn_mfma_f32_16x16x32_bf16(ka1, qa1, sa, 0, 0, 0);
        sb = __builtin_amdgcn_mfma_f32_16x16x32_bf16(kb0, qa0, sb, 0, 0, 0);
        sb = __builtin_amdgcn_mfma_f32_16x16x32_bf16(kb1, qa1, sb, 0, 0, 0);

        s16x4 pa, pb;
        float ea0 = hw_exp2(sa[0] + fmaf(ma[0], MASK_L2, -MASK_L2));
        float ea1 = hw_exp2(sa[1] + fmaf(ma[1], MASK_L2, -MASK_L2));
        float ea2 = hw_exp2(sa[2] + fmaf(ma[2], MASK_L2, -MASK_L2));
        float ea3 = hw_exp2(sa[3] + fmaf(ma[3], MASK_L2, -MASK_L2));
        float eb0 = hw_exp2(sb[0] + fmaf(mb[0], MASK_L2, -MASK_L2));
        float eb1 = hw_exp2(sb[1] + fmaf(mb[1], MASK_L2, -MASK_L2));
        float eb2 = hw_exp2(sb[2] + fmaf(mb[2], MASK_L2, -MASK_L2));
        float eb3 = hw_exp2(sb[3] + fmaf(mb[3], MASK_L2, -MASK_L2));
        pa[0] = (short)__builtin_bit_cast(unsigned short, (__bf16)ea0);
        pa[1] = (short)__builtin_bit_cast(unsigned short, (__bf16)ea1);
        pa[2] = (short)__builtin_bit_cast(unsigned short, (__bf16)ea2);
        pa[3] = (short)__builtin_bit_cast(unsigned short, (__bf16)ea3);
        pb[0] = (short)__builtin_bit_cast(unsigned short, (__bf16)eb0);
        pb[1] = (short)__builtin_bit_cast(unsigned short, (__bf16)eb1);
        pb[2] = (short)__builtin_bit_cast(unsigned short, (__bf16)eb2);
        pb[3] = (short)__builtin_bit_cast(unsigned short, (__bf16)eb3);

        lsl += ((ea0 + ea1) + (ea2 + ea3)) + ((eb0 + eb1) + (eb2 + eb3));

        o0 = mfma_pv(va0, pa, o0); o0 = mfma_pv(vb0, pb, o0);
        o1 = mfma_pv(va1, pa, o1); o1 = mfma_pv(vb1, pb, o1);
        o2 = mfma_pv(va2, pa, o2); o2 = mfma_pv(vb2, pb, o2);
        o3 = mfma_pv(va3, pa, o3); o3 = mfma_pv(vb3, pb, o3);
    }

    // row sum for q=n: combine the 4 quad-groups (lanes n, n+16, n+32, n+48)
    float rs = lsl;
    rs += __shfl_xor(rs, 16);
    rs += __shfl_xor(rs, 32);
    const float inv = 1.0f / rs;

    // O^T -> O via per-wave LDS tile, then coalesced 16B stores
    #pragma unroll
    for (int r = 0; r < 4; ++r) {
        et[w][n][ 0 + 4 * g + r] = o0[r] * inv;
        et[w][n][16 + 4 * g + r] = o1[r] * inv;
        et[w][n][32 + 4 * g + r] = o2[r] * inv;
        et[w][n][48 + 4 * g + r] = o3[r] * inv;
    }
    float* obase = out + ((size_t)(b_ * SEQ + q0 + n)) * NP + h * HD;
    #pragma unroll
    for (int j = 0; j < 4; ++j) {
        *(f32x4*)(obase + 16 * g + 4 * j) = *(const f32x4*)(&et[w][n][16 * g + 4 * j]);
    }
}

extern "C" void kernel_launch(void* const* d_in, const int* in_sizes, int n_in,
                              void* d_out, int out_size, void* d_ws, size_t ws_size,
                              hipStream_t stream) {
    const float* hidden = (const float*)d_in[0];
    const float* amask  = (const float*)d_in[1];
    const float* Wq     = (const float*)d_in[2];
    const float* bq     = (const float*)d_in[3];
    const float* Wk     = (const float*)d_in[4];
    const float* bk     = (const float*)d_in[5];
    const float* Wv     = (const float*)d_in[6];
    const float* bv     = (const float*)d_in[7];
    float* out = (float*)d_out;

    const size_t elems = (size_t)NB * NH * SEQ * HD; // 6,291,456
    __bf16* Qw  = (__bf16*)d_ws;
    __bf16* Kw  = Qw + elems;
    __bf16* Vtw = Kw + elems;
    __bf16* Wt  = Vtw + elems;   // 3*768*64 bf16 = 294 KB extra

    wt_kernel<<<dim3(12, 3), 256, 0, stream>>>(Wq, Wk, Wv, Wt);

    qkv_kernel<<<dim3(768), 256, 0, stream>>>(
        hidden, Wt, bq, bk, bv, Qw, Kw, Vtw);

    flash_attn_kernel<<<dim3(48 * 32), 256, 0, stream>>>(
        Qw, Kw, Vtw, amask, out);
}

// Round 6
// 302.003 us; speedup vs baseline: 2.1053x; 2.1053x over previous
//
#include <hip/hip_runtime.h>
#include <hip/hip_bf16.h>

#define NH 12
#define HD 64
#define NB 4
#define SEQ 2048
#define NP 768
#define LOG2E 1.44269504f
#define MASK_L2 14426.9504f   // 10000 * log2(e)

typedef __bf16 bf16x8 __attribute__((ext_vector_type(8)));
typedef float f32x4 __attribute__((ext_vector_type(4)));
typedef float f32x16 __attribute__((ext_vector_type(16)));
typedef unsigned u32x4 __attribute__((ext_vector_type(4)));

static __device__ __forceinline__ bf16x8 load_bf16x8(const __bf16* p) {
    return *reinterpret_cast<const bf16x8*>(p);
}
static __device__ __forceinline__ float hw_exp2(float x) {
    return __builtin_amdgcn_exp2f(x);
}
static __device__ __forceinline__ unsigned pack_bf16(float lo, float hi) {
    unsigned a = (unsigned)__builtin_bit_cast(unsigned short, (__bf16)lo);
    unsigned b = (unsigned)__builtin_bit_cast(unsigned short, (__bf16)hi);
    return a | (b << 16);
}

// ---------------------------------------------------------------------------
// Kernel 0: W (64,768) fp32 -> Wt (768,64) bf16, 0.125*log2e folded for Q.
// ---------------------------------------------------------------------------
__global__ __launch_bounds__(256) void wt_kernel(
    const float* __restrict__ Wq, const float* __restrict__ Wk,
    const float* __restrict__ Wv, __bf16* __restrict__ Wt)
{
    __shared__ float tile[64][69];
    const int by = blockIdx.y;
    const float* W = by == 0 ? Wq : (by == 1 ? Wk : Wv);
    const float scale = (by == 0) ? 0.125f * LOG2E : 1.0f;
    const int p0 = blockIdx.x * 64;
    const int tl = threadIdx.x & 63;
    const int tq = threadIdx.x >> 6;
    #pragma unroll
    for (int i = 0; i < 16; ++i) {
        const int d = tq + 4 * i;
        tile[tl][d] = W[(size_t)d * NP + p0 + tl];
    }
    __syncthreads();
    #pragma unroll
    for (int i = 0; i < 16; ++i) {
        const int pl = tq + 4 * i;
        Wt[((size_t)by * NP + p0 + pl) * HD + tl] = (__bf16)(tile[pl][tl] * scale);
    }
}

// ---------------------------------------------------------------------------
// Kernel 1: QKV projection (transposed bf16 weights, contiguous 16B operands).
// Q,K -> (B*H, T, 64); V -> transposed (B*H, 64, T). grid = 768.
// ---------------------------------------------------------------------------
__global__ __launch_bounds__(256) void qkv_kernel(
    const float* __restrict__ hidden, const __bf16* __restrict__ Wt,
    const float* __restrict__ bq, const float* __restrict__ bk,
    const float* __restrict__ bv,
    __bf16* __restrict__ Qw, __bf16* __restrict__ Kw, __bf16* __restrict__ Vtw)
{
    const int lane = threadIdx.x & 63;
    const int w    = threadIdx.x >> 6;
    const int g    = lane >> 4;
    const int n    = lane & 15;

    const int bid    = blockIdx.x;
    const int pi     = bid >> 8;
    const int pchunk = (bid >> 7) & 1;
    const int rblk   = bid & 127;
    const int row0   = rblk * 64 + w * 16;
    const int b_     = row0 >> 11;
    const int t0     = row0 & (SEQ - 1);

    const float* bias = pi == 0 ? bq : (pi == 1 ? bk : bv);
    const float qs = (pi == 0) ? 0.125f * LOG2E : 1.0f;
    const __bf16* Wtp = Wt + (size_t)pi * NP * HD;

    const float* hrow = hidden + (size_t)(row0 + n) * HD + 8 * g;
    f32x4 h0 = *(const f32x4*)(hrow);
    f32x4 h1 = *(const f32x4*)(hrow + 4);
    f32x4 h2 = *(const f32x4*)(hrow + 32);
    f32x4 h3 = *(const f32x4*)(hrow + 36);
    bf16x8 a0, a1;
    #pragma unroll
    for (int j = 0; j < 4; ++j) {
        a0[j]     = (__bf16)h0[j];
        a0[j + 4] = (__bf16)h1[j];
        a1[j]     = (__bf16)h2[j];
        a1[j + 4] = (__bf16)h3[j];
    }

    for (int pt = pchunk * 24; pt < pchunk * 24 + 24; ++pt) {
        const int pbase = pt * 16;
        const __bf16* wp = Wtp + (size_t)(pbase + n) * HD + 8 * g;
        bf16x8 w0 = load_bf16x8(wp);
        bf16x8 w1 = load_bf16x8(wp + 32);

        f32x4 acc = {0.f, 0.f, 0.f, 0.f};
        acc = __builtin_amdgcn_mfma_f32_16x16x32_bf16(a0, w0, acc, 0, 0, 0);
        acc = __builtin_amdgcn_mfma_f32_16x16x32_bf16(a1, w1, acc, 0, 0, 0);

        const float bb  = bias[pbase + n] * qs;
        const int h     = pbase >> 6;
        const int dbase = pbase & 63;
        const int bh    = b_ * NH + h;

        if (pi < 2) {
            __bf16* dst = (pi == 0 ? Qw : Kw) + ((size_t)bh * SEQ) * HD + dbase + n;
            #pragma unroll
            for (int r = 0; r < 4; ++r)
                dst[(size_t)(t0 + 4 * g + r) * HD] = (__bf16)(acc[r] + bb);
        } else {
            __bf16* dst = Vtw + ((size_t)bh * HD + dbase + n) * SEQ;
            #pragma unroll
            for (int r = 0; r < 4; ++r)
                dst[t0 + 4 * g + r] = (__bf16)(acc[r] + bb);
        }
    }
}

// ---------------------------------------------------------------------------
// Kernel 2 v5: flash attention, 32x32x16 MFMAs. Wave owns 32 q x 64 d.
// Per 32-key iter: 4 S^T MFMAs (A=K, B=Q), exp2 (mask folded), pack to bf16,
// half-wave exchange (shfl_xor 32 + cndmask) to build the PV B-operand from
// the S^T C-layout, 4 PV MFMAs (A=V^T). K prefetched one iter ahead; V/mask
// issued at iter top. No LDS/barriers in the loop; no launch_bounds cap so
// the allocator can hold the prefetch in VGPRs (v4's 32-VGPR collapse).
// ---------------------------------------------------------------------------
__global__ __launch_bounds__(256) void flash_attn_kernel(
    const __bf16* __restrict__ Qw, const __bf16* __restrict__ Kw,
    const __bf16* __restrict__ Vtw, const float* __restrict__ amask,
    float* __restrict__ out)
{
    __shared__ float et[4][32][68];

    const int lane = threadIdx.x & 63;
    const int w    = threadIdx.x >> 6;
    const int n32  = lane & 31;
    const int hi   = lane >> 5;

    const int bid    = blockIdx.x;        // 768
    const int xcd    = bid & 7;
    const int slot   = bid >> 3;          // 0..95
    const int bh     = xcd * 6 + (slot >> 4);
    const int qchunk = slot & 15;
    const int b_     = bh / NH;
    const int h      = bh % NH;
    const int q0     = qchunk * 128 + w * 32;

    // Q as B-operand: B[k=16*dstep+8*hi+j][q=n32] = Q[q0+n32][...]
    const __bf16* Qrow = Qw + ((size_t)bh * SEQ + q0 + n32) * HD + 8 * hi;
    bf16x8 qf[4];
    #pragma unroll
    for (int dstep = 0; dstep < 4; ++dstep)
        qf[dstep] = load_bf16x8(Qrow + dstep * 16);

    const __bf16* Krow = Kw + ((size_t)bh * SEQ + n32) * HD + 8 * hi;
    const __bf16* Vr0  = Vtw + ((size_t)bh * HD + n32) * SEQ;        // d tile 0
    const __bf16* Vr1  = Vtw + ((size_t)bh * HD + 32 + n32) * SEQ;   // d tile 1
    const float*  mp   = amask + (size_t)b_ * SEQ;

    // O^T accumulators: o[dt][r] = O^T[32dt + (r&3)+8(r>>2)+4hi][q=n32]
    f32x16 o0 = {0,0,0,0,0,0,0,0,0,0,0,0,0,0,0,0};
    f32x16 o1 = {0,0,0,0,0,0,0,0,0,0,0,0,0,0,0,0};
    float lsl = 0.f;

    // K fragment for kb=0
    bf16x8 ck0 = load_bf16x8(Krow);
    bf16x8 ck1 = load_bf16x8(Krow + 16);
    bf16x8 ck2 = load_bf16x8(Krow + 32);
    bf16x8 ck3 = load_bf16x8(Krow + 48);

    for (int kb = 0; kb < SEQ; kb += 32) {
        // prefetch next iteration's K (wraps harmlessly on last iter)
        const int nkb = (kb + 32) & (SEQ - 1);
        const __bf16* nKrow = Krow + (size_t)nkb * HD;
        bf16x8 nk0 = load_bf16x8(nKrow);
        bf16x8 nk1 = load_bf16x8(nKrow + 16);
        bf16x8 nk2 = load_bf16x8(nKrow + 32);
        bf16x8 nk3 = load_bf16x8(nKrow + 48);

        // V^T fragments for this iter (used after exp — latency overlapped)
        const int vo = kb + 8 * hi;
        bf16x8 v00 = load_bf16x8(Vr0 + vo);        // dt=0, e=0
        bf16x8 v01 = load_bf16x8(Vr0 + vo + 16);   // dt=0, e=1
        bf16x8 v10 = load_bf16x8(Vr1 + vo);        // dt=1, e=0
        bf16x8 v11 = load_bf16x8(Vr1 + vo + 16);   // dt=1, e=1

        // mask quads: mq[qd][i] masks key kb + 8*qd + 4*hi + i
        f32x4 mq0 = *(const f32x4*)(mp + kb + 4 * hi);
        f32x4 mq1 = *(const f32x4*)(mp + kb + 8 + 4 * hi);
        f32x4 mq2 = *(const f32x4*)(mp + kb + 16 + 4 * hi);
        f32x4 mq3 = *(const f32x4*)(mp + kb + 24 + 4 * hi);

        // S^T[key][q] over d=64 (log2 domain; scale folded into Q)
        f32x16 s = {0,0,0,0,0,0,0,0,0,0,0,0,0,0,0,0};
        s = __builtin_amdgcn_mfma_f32_32x32x16_bf16(ck0, qf[0], s, 0, 0, 0);
        s = __builtin_amdgcn_mfma_f32_32x32x16_bf16(ck1, qf[1], s, 0, 0, 0);
        s = __builtin_amdgcn_mfma_f32_32x32x16_bf16(ck2, qf[2], s, 0, 0, 0);
        s = __builtin_amdgcn_mfma_f32_32x32x16_bf16(ck3, qf[3], s, 0, 0, 0);

        // p[r] = exp2(s[r] + mask); reg r -> key (r&3) + 8*(r>>2) + 4*hi
        float p[16];
        #pragma unroll
        for (int r = 0; r < 16; ++r) {
            const float mv = (r >> 2) == 0 ? mq0[r & 3]
                           : (r >> 2) == 1 ? mq1[r & 3]
                           : (r >> 2) == 2 ? mq2[r & 3] : mq3[r & 3];
            p[r] = hw_exp2(s[r] + fmaf(mv, MASK_L2, -MASK_L2));
            lsl += p[r];
        }

        // pack quads into dwords: pk[2q+i] = keys {4q+2i, 4q+2i+1} (this hi)
        unsigned pk[8], xp[8];
        #pragma unroll
        for (int i = 0; i < 8; ++i) pk[i] = pack_bf16(p[2 * i], p[2 * i + 1]);
        #pragma unroll
        for (int i = 0; i < 8; ++i) xp[i] = __shfl_xor(pk[i], 32);

        // PV B-operand (k = 8*hi + j) from own/partner quads:
        // e=0 keys 0..15, e=1 keys 16..31
        u32x4 B0, B1;
        B0[0] = hi ? xp[2] : pk[0];  B0[1] = hi ? xp[3] : pk[1];
        B0[2] = hi ? pk[2] : xp[0];  B0[3] = hi ? pk[3] : xp[1];
        B1[0] = hi ? xp[6] : pk[4];  B1[1] = hi ? xp[7] : pk[5];
        B1[2] = hi ? pk[6] : xp[4];  B1[3] = hi ? pk[7] : xp[5];
        const bf16x8 pb0 = __builtin_bit_cast(bf16x8, B0);
        const bf16x8 pb1 = __builtin_bit_cast(bf16x8, B1);

        o0 = __builtin_amdgcn_mfma_f32_32x32x16_bf16(v00, pb0, o0, 0, 0, 0);
        o0 = __builtin_amdgcn_mfma_f32_32x32x16_bf16(v01, pb1, o0, 0, 0, 0);
        o1 = __builtin_amdgcn_mfma_f32_32x32x16_bf16(v10, pb0, o1, 0, 0, 0);
        o1 = __builtin_amdgcn_mfma_f32_32x32x16_bf16(v11, pb1, o1, 0, 0, 0);

        ck0 = nk0; ck1 = nk1; ck2 = nk2; ck3 = nk3;
    }

    // each q lives on lanes n32 and n32+32 (different key halves)
    const float rs  = lsl + __shfl_xor(lsl, 32);
    const float inv = 1.0f / rs;

    // O^T -> O via per-wave LDS tile (same-wave RAW: no barrier needed)
    #pragma unroll
    for (int r = 0; r < 16; ++r) {
        const int dl = (r & 3) + 8 * (r >> 2) + 4 * hi;
        et[w][n32][dl]      = o0[r] * inv;
        et[w][n32][32 + dl] = o1[r] * inv;
    }
    float* orow = out + ((size_t)(b_ * SEQ + q0 + n32)) * NP + h * HD + 32 * hi;
    #pragma unroll
    for (int j = 0; j < 8; ++j) {
        *(f32x4*)(orow + 4 * j) = *(const f32x4*)(&et[w][n32][32 * hi + 4 * j]);
    }
}

extern "C" void kernel_launch(void* const* d_in, const int* in_sizes, int n_in,
                              void* d_out, int out_size, void* d_ws, size_t ws_size,
                              hipStream_t stream) {
    const float* hidden = (const float*)d_in[0];
    const float* amask  = (const float*)d_in[1];
    const float* Wq     = (const float*)d_in[2];
    const float* bq     = (const float*)d_in[3];
    const float* Wk     = (const float*)d_in[4];
    const float* bk     = (const float*)d_in[5];
    const float* Wv     = (const float*)d_in[6];
    const float* bv     = (const float*)d_in[7];
    float* out = (float*)d_out;

    const size_t elems = (size_t)NB * NH * SEQ * HD; // 6,291,456
    __bf16* Qw  = (__bf16*)d_ws;
    __bf16* Kw  = Qw + elems;
    __bf16* Vtw = Kw + elems;
    __bf16* Wt  = Vtw + elems;   // 3*768*64 bf16

    wt_kernel<<<dim3(12, 3), 256, 0, stream>>>(Wq, Wk, Wv, Wt);

    qkv_kernel<<<dim3(768), 256, 0, stream>>>(
        hidden, Wt, bq, bk, bv, Qw, Kw, Vtw);

    flash_attn_kernel<<<dim3(768), 256, 0, stream>>>(
        Qw, Kw, Vtw, amask, out);
}

// Round 7
// 222.282 us; speedup vs baseline: 2.8604x; 1.3586x over previous
//
#include <hip/hip_runtime.h>
#include <hip/hip_bf16.h>

#define NH 12
#define HD 64
#define NB 4
#define SEQ 2048
#define NP 768
#define LOG2E 1.44269504f
#define MASK_L2 14426.9504f   // 10000 * log2(e)

typedef __bf16 bf16x8 __attribute__((ext_vector_type(8)));
typedef float f32x4 __attribute__((ext_vector_type(4)));
typedef float f32x16 __attribute__((ext_vector_type(16)));
typedef unsigned u32x4 __attribute__((ext_vector_type(4)));

static __device__ __forceinline__ bf16x8 load_bf16x8(const __bf16* p) {
    return *reinterpret_cast<const bf16x8*>(p);
}
static __device__ __forceinline__ float hw_exp2(float x) {
    return __builtin_amdgcn_exp2f(x);
}
static __device__ __forceinline__ unsigned pack_bf16(float lo, float hi) {
    unsigned a = (unsigned)__builtin_bit_cast(unsigned short, (__bf16)lo);
    unsigned b = (unsigned)__builtin_bit_cast(unsigned short, (__bf16)hi);
    return a | (b << 16);
}

// ---------------------------------------------------------------------------
// Kernel 0: W (64,768) fp32 -> Wt (768,64) bf16, 0.125*log2e folded for Q.
// ---------------------------------------------------------------------------
__global__ __launch_bounds__(256) void wt_kernel(
    const float* __restrict__ Wq, const float* __restrict__ Wk,
    const float* __restrict__ Wv, __bf16* __restrict__ Wt)
{
    __shared__ float tile[64][69];
    const int by = blockIdx.y;
    const float* W = by == 0 ? Wq : (by == 1 ? Wk : Wv);
    const float scale = (by == 0) ? 0.125f * LOG2E : 1.0f;
    const int p0 = blockIdx.x * 64;
    const int tl = threadIdx.x & 63;
    const int tq = threadIdx.x >> 6;
    #pragma unroll
    for (int i = 0; i < 16; ++i) {
        const int d = tq + 4 * i;
        tile[tl][d] = W[(size_t)d * NP + p0 + tl];
    }
    __syncthreads();
    #pragma unroll
    for (int i = 0; i < 16; ++i) {
        const int pl = tq + 4 * i;
        Wt[((size_t)by * NP + p0 + pl) * HD + tl] = (__bf16)(tile[pl][tl] * scale);
    }
}

// ---------------------------------------------------------------------------
// Kernel 1 v6: QKV projection with coalesced epilogue.
// Block = 64 t-rows; grid (128 tblk, 4 groups); each group does 9 of the 36
// (proj, head-64d) tiles. C staged in padded LDS -> 16B coalesced stores for
// Q/K and the V-transpose (v5 scattered 2-B stores were transaction-bound).
// ---------------------------------------------------------------------------
__global__ __launch_bounds__(256) void qkv_kernel(
    const float* __restrict__ hidden, const __bf16* __restrict__ Wt,
    const float* __restrict__ bq, const float* __restrict__ bk,
    const float* __restrict__ bv,
    __bf16* __restrict__ Qw, __bf16* __restrict__ Kw, __bf16* __restrict__ Vtw)
{
    __shared__ __bf16 ot[64][68];   // 64 t x 64 d (+4 pad)

    const int tid  = threadIdx.x;
    const int lane = tid & 63;
    const int w    = tid >> 6;
    const int g    = lane >> 4;
    const int n    = lane & 15;

    const int row0 = blockIdx.x * 64;
    const int gi   = blockIdx.y;          // 0..3
    const int b_   = row0 >> 11;
    const int t0   = row0 & (SEQ - 1);

    // A fragments: wave w owns rows row0 + w*16 (+n), K=64 via two frags
    const float* hrow = hidden + (size_t)(row0 + w * 16 + n) * HD + 8 * g;
    f32x4 h0 = *(const f32x4*)(hrow);
    f32x4 h1 = *(const f32x4*)(hrow + 4);
    f32x4 h2 = *(const f32x4*)(hrow + 32);
    f32x4 h3 = *(const f32x4*)(hrow + 36);
    bf16x8 a0, a1;
    #pragma unroll
    for (int j = 0; j < 4; ++j) {
        a0[j]     = (__bf16)h0[j];
        a0[j + 4] = (__bf16)h1[j];
        a1[j]     = (__bf16)h2[j];
        a1[j + 4] = (__bf16)h3[j];
    }

    for (int tt = 0; tt < 9; ++tt) {
        const int tile_id = gi * 9 + tt;       // 0..35
        const int proj    = tile_id / 12;
        const int head    = tile_id % 12;
        const int bh      = b_ * NH + head;
        const float* bias = proj == 0 ? bq : (proj == 1 ? bk : bv);
        const float qs    = (proj == 0) ? 0.125f * LOG2E : 1.0f;
        const __bf16* Wp  = Wt + ((size_t)proj * NP + head * 64) * HD;

        // all 4 d-tile fragment loads issued up front (latency overlap)
        bf16x8 w0[4], w1[4];
        #pragma unroll
        for (int dt = 0; dt < 4; ++dt) {
            const __bf16* wp = Wp + (size_t)(dt * 16 + n) * HD + 8 * g;
            w0[dt] = load_bf16x8(wp);
            w1[dt] = load_bf16x8(wp + 32);
        }
        #pragma unroll
        for (int dt = 0; dt < 4; ++dt) {
            f32x4 acc = {0.f, 0.f, 0.f, 0.f};
            acc = __builtin_amdgcn_mfma_f32_16x16x32_bf16(a0, w0[dt], acc, 0, 0, 0);
            acc = __builtin_amdgcn_mfma_f32_16x16x32_bf16(a1, w1[dt], acc, 0, 0, 0);
            const float bb = bias[head * 64 + dt * 16 + n] * qs;
            #pragma unroll
            for (int r = 0; r < 4; ++r)
                ot[w * 16 + 4 * g + r][dt * 16 + n] = (__bf16)(acc[r] + bb);
        }
        __syncthreads();

        if (proj < 2) {
            // contiguous 8 KB tile: thread writes 32 B
            __bf16* dst = (proj ? Kw : Qw) + ((size_t)bh * SEQ + t0) * HD;
            const int trow = tid >> 2;
            const int d0   = (tid & 3) * 16;
            *(bf16x8*)(dst + (size_t)trow * HD + d0)     = *(const bf16x8*)&ot[trow][d0];
            *(bf16x8*)(dst + (size_t)trow * HD + d0 + 8) = *(const bf16x8*)&ot[trow][d0 + 8];
        } else {
            // V^T: row d gets 64 t's; gather-transpose from LDS, 16B stores
            #pragma unroll
            for (int R = 0; R < 2; ++R) {
                const int d  = R * 32 + (tid >> 3);
                const int tc = (tid & 7) * 8;
                bf16x8 v;
                #pragma unroll
                for (int j = 0; j < 8; ++j) v[j] = ot[tc + j][d];
                *(bf16x8*)(Vtw + ((size_t)bh * HD + d) * SEQ + t0 + tc) = v;
            }
        }
        __syncthreads();
    }
}

// ---------------------------------------------------------------------------
// Kernel 2 v6: flash attention, 32x32x16 MFMAs + LDS-staged K/V tiles.
// K-step 64. Per iter: coalesced global->reg prefetch of next K/V tile,
// ds_write_b128 into padded (72-elem) rows, conflict-free ds_read_b128
// fragments, 8 S^T MFMAs, exp2 + pack + half-wave exchange (v5-verified),
// 8 PV MFMAs. Epilogue O^T->O via LDS (union with staging buffers).
// ---------------------------------------------------------------------------
__global__ __launch_bounds__(256) void flash_attn_kernel(
    const __bf16* __restrict__ Qw, const __bf16* __restrict__ Kw,
    const __bf16* __restrict__ Vtw, const float* __restrict__ amask,
    float* __restrict__ out)
{
    __shared__ __align__(16) char smem[34816];   // max(2*9216 staging, et)
    __bf16 (*kt)[72] = (__bf16(*)[72])smem;            // 64 x 72 = 9216 B
    __bf16 (*vt)[72] = (__bf16(*)[72])(smem + 9216);   // 64 x 72
    float (*et)[32][68] = (float(*)[32][68])smem;      // epilogue alias

    const int tid  = threadIdx.x;
    const int lane = tid & 63;
    const int w    = tid >> 6;
    const int n32  = lane & 31;
    const int hi   = lane >> 5;

    const int bid    = blockIdx.x;        // 768
    const int xcd    = bid & 7;
    const int slot   = bid >> 3;          // 0..95
    const int bh     = xcd * 6 + (slot >> 4);
    const int qchunk = slot & 15;
    const int b_     = bh / NH;
    const int h      = bh % NH;
    const int q0     = qchunk * 128 + w * 32;

    // Q as B-operand: B[k=16*dstep+8*hi+j][q=n32]
    const __bf16* Qrow = Qw + ((size_t)bh * SEQ + q0 + n32) * HD + 8 * hi;
    bf16x8 qf[4];
    #pragma unroll
    for (int dstep = 0; dstep < 4; ++dstep)
        qf[dstep] = load_bf16x8(Qrow + dstep * 16);

    const __bf16* Kbh = Kw  + (size_t)bh * SEQ * HD;
    const __bf16* Vbh = Vtw + (size_t)bh * HD * SEQ;
    const float*  mp  = amask + (size_t)b_ * SEQ;

    // staging map: thread tid, round R: K row R*32+tid/8, col (tid&7)*8
    const int srow = tid >> 3;            // 0..31
    const int scol = (tid & 7) * 8;       // elements

    // prefetch tile kb=0 into regs
    bf16x8 kreg[2], vreg[2];
    #pragma unroll
    for (int R = 0; R < 2; ++R) {
        kreg[R] = load_bf16x8(Kbh + (size_t)(R * 32 + srow) * HD + scol);
        vreg[R] = load_bf16x8(Vbh + (size_t)(R * 32 + srow) * SEQ + scol);
    }

    // O^T accumulators: o0 d-rows n32(+4hi..), o1 d-rows 32+n32
    f32x16 o0 = {0,0,0,0,0,0,0,0,0,0,0,0,0,0,0,0};
    f32x16 o1 = {0,0,0,0,0,0,0,0,0,0,0,0,0,0,0,0};
    float lsl = 0.f;

    for (int kb = 0; kb < SEQ; kb += 64) {
        __syncthreads();    // previous iter's LDS reads complete
        #pragma unroll
        for (int R = 0; R < 2; ++R) {
            *(bf16x8*)&kt[R * 32 + srow][scol] = kreg[R];
            *(bf16x8*)&vt[R * 32 + srow][scol] = vreg[R];
        }
        __syncthreads();    // tile visible

        // prefetch next tile (wraps harmlessly); flies during compute
        const int nkb = (kb + 64) & (SEQ - 1);
        #pragma unroll
        for (int R = 0; R < 2; ++R) {
            kreg[R] = load_bf16x8(Kbh + (size_t)nkb * HD + (size_t)(R * 32 + srow) * HD + scol);
            vreg[R] = load_bf16x8(Vbh + (size_t)(R * 32 + srow) * SEQ + nkb + scol);
        }

        // K fragments: subtile a = keys kb..kb+31 (rows n32), b = +32
        bf16x8 kfa[4], kfb[4];
        #pragma unroll
        for (int dstep = 0; dstep < 4; ++dstep) {
            kfa[dstep] = *(const bf16x8*)&kt[n32][dstep * 16 + 8 * hi];
            kfb[dstep] = *(const bf16x8*)&kt[32 + n32][dstep * 16 + 8 * hi];
        }
        // V fragments: o0 rows n32, o1 rows 32+n32; key-steps 0..3
        bf16x8 vf0[4], vf1[4];
        #pragma unroll
        for (int ks = 0; ks < 4; ++ks) {
            vf0[ks] = *(const bf16x8*)&vt[n32][ks * 16 + 8 * hi];
            vf1[ks] = *(const bf16x8*)&vt[32 + n32][ks * 16 + 8 * hi];
        }

        // S^T (log2 domain; 0.125*log2e folded into Q)
        f32x16 sa = {0,0,0,0,0,0,0,0,0,0,0,0,0,0,0,0};
        f32x16 sb = {0,0,0,0,0,0,0,0,0,0,0,0,0,0,0,0};
        #pragma unroll
        for (int dstep = 0; dstep < 4; ++dstep) {
            sa = __builtin_amdgcn_mfma_f32_32x32x16_bf16(kfa[dstep], qf[dstep], sa, 0, 0, 0);
            sb = __builtin_amdgcn_mfma_f32_32x32x16_bf16(kfb[dstep], qf[dstep], sb, 0, 0, 0);
        }

        // exp2 + pack + half-wave exchange, per 32-key half (v5-verified)
        bf16x8 pA0, pA1, pB0, pB1;
        #pragma unroll
        for (int half = 0; half < 2; ++half) {
            const f32x16& s = half ? sb : sa;
            const int mbase = kb + 32 * half;
            f32x4 mq0 = *(const f32x4*)(mp + mbase + 4 * hi);
            f32x4 mq1 = *(const f32x4*)(mp + mbase + 8 + 4 * hi);
            f32x4 mq2 = *(const f32x4*)(mp + mbase + 16 + 4 * hi);
            f32x4 mq3 = *(const f32x4*)(mp + mbase + 24 + 4 * hi);
            float p[16];
            #pragma unroll
            for (int r = 0; r < 16; ++r) {
                const float mv = (r >> 2) == 0 ? mq0[r & 3]
                               : (r >> 2) == 1 ? mq1[r & 3]
                               : (r >> 2) == 2 ? mq2[r & 3] : mq3[r & 3];
                p[r] = hw_exp2(s[r] + fmaf(mv, MASK_L2, -MASK_L2));
                lsl += p[r];
            }
            unsigned pk[8], xp[8];
            #pragma unroll
            for (int i = 0; i < 8; ++i) pk[i] = pack_bf16(p[2 * i], p[2 * i + 1]);
            #pragma unroll
            for (int i = 0; i < 8; ++i) xp[i] = __shfl_xor(pk[i], 32);
            u32x4 B0, B1;
            B0[0] = hi ? xp[2] : pk[0];  B0[1] = hi ? xp[3] : pk[1];
            B0[2] = hi ? pk[2] : xp[0];  B0[3] = hi ? pk[3] : xp[1];
            B1[0] = hi ? xp[6] : pk[4];  B1[1] = hi ? xp[7] : pk[5];
            B1[2] = hi ? pk[6] : xp[4];  B1[3] = hi ? pk[7] : xp[5];
            if (half == 0) { pA0 = __builtin_bit_cast(bf16x8, B0); pA1 = __builtin_bit_cast(bf16x8, B1); }
            else           { pB0 = __builtin_bit_cast(bf16x8, B0); pB1 = __builtin_bit_cast(bf16x8, B1); }
        }

        o0 = __builtin_amdgcn_mfma_f32_32x32x16_bf16(vf0[0], pA0, o0, 0, 0, 0);
        o0 = __builtin_amdgcn_mfma_f32_32x32x16_bf16(vf0[1], pA1, o0, 0, 0, 0);
        o0 = __builtin_amdgcn_mfma_f32_32x32x16_bf16(vf0[2], pB0, o0, 0, 0, 0);
        o0 = __builtin_amdgcn_mfma_f32_32x32x16_bf16(vf0[3], pB1, o0, 0, 0, 0);
        o1 = __builtin_amdgcn_mfma_f32_32x32x16_bf16(vf1[0], pA0, o1, 0, 0, 0);
        o1 = __builtin_amdgcn_mfma_f32_32x32x16_bf16(vf1[1], pA1, o1, 0, 0, 0);
        o1 = __builtin_amdgcn_mfma_f32_32x32x16_bf16(vf1[2], pB0, o1, 0, 0, 0);
        o1 = __builtin_amdgcn_mfma_f32_32x32x16_bf16(vf1[3], pB1, o1, 0, 0, 0);
    }

    // each q lives on lanes n32 and n32+32
    const float rs  = lsl + __shfl_xor(lsl, 32);
    const float inv = 1.0f / rs;

    __syncthreads();   // staging done everywhere before aliasing as et

    #pragma unroll
    for (int r = 0; r < 16; ++r) {
        const int dl = (r & 3) + 8 * (r >> 2) + 4 * hi;
        et[w][n32][dl]      = o0[r] * inv;
        et[w][n32][32 + dl] = o1[r] * inv;
    }
    float* orow = out + ((size_t)(b_ * SEQ + q0 + n32)) * NP + h * HD + 32 * hi;
    #pragma unroll
    for (int j = 0; j < 8; ++j) {
        *(f32x4*)(orow + 4 * j) = *(const f32x4*)(&et[w][n32][32 * hi + 4 * j]);
    }
}

extern "C" void kernel_launch(void* const* d_in, const int* in_sizes, int n_in,
                              void* d_out, int out_size, void* d_ws, size_t ws_size,
                              hipStream_t stream) {
    const float* hidden = (const float*)d_in[0];
    const float* amask  = (const float*)d_in[1];
    const float* Wq     = (const float*)d_in[2];
    const float* bq     = (const float*)d_in[3];
    const float* Wk     = (const float*)d_in[4];
    const float* bk     = (const float*)d_in[5];
    const float* Wv     = (const float*)d_in[6];
    const float* bv     = (const float*)d_in[7];
    float* out = (float*)d_out;

    const size_t elems = (size_t)NB * NH * SEQ * HD; // 6,291,456
    __bf16* Qw  = (__bf16*)d_ws;
    __bf16* Kw  = Qw + elems;
    __bf16* Vtw = Kw + elems;
    __bf16* Wt  = Vtw + elems;   // 3*768*64 bf16

    wt_kernel<<<dim3(12, 3), 256, 0, stream>>>(Wq, Wk, Wv, Wt);

    qkv_kernel<<<dim3(128, 4), 256, 0, stream>>>(
        hidden, Wt, bq, bk, bv, Qw, Kw, Vtw);

    flash_attn_kernel<<<dim3(768), 256, 0, stream>>>(
        Qw, Kw, Vtw, amask, out);
}

// Round 8
// 190.251 us; speedup vs baseline: 3.3420x; 1.1684x over previous
//
#include <hip/hip_runtime.h>
#include <hip/hip_bf16.h>

#define NH 12
#define HD 64
#define NB 4
#define SEQ 2048
#define NP 768
#define LOG2E 1.44269504f
#define MASK_L2 14426.9504f   // 10000 * log2(e)

typedef __bf16 bf16x8 __attribute__((ext_vector_type(8)));
typedef float f32x4 __attribute__((ext_vector_type(4)));
typedef float f32x16 __attribute__((ext_vector_type(16)));
typedef unsigned u32x4 __attribute__((ext_vector_type(4)));

static __device__ __forceinline__ bf16x8 load_bf16x8(const __bf16* p) {
    return *reinterpret_cast<const bf16x8*>(p);
}
static __device__ __forceinline__ float hw_exp2(float x) {
    return __builtin_amdgcn_exp2f(x);
}
static __device__ __forceinline__ unsigned pack_bf16(float lo, float hi) {
    unsigned a = (unsigned)__builtin_bit_cast(unsigned short, (__bf16)lo);
    unsigned b = (unsigned)__builtin_bit_cast(unsigned short, (__bf16)hi);
    return a | (b << 16);
}

// ---------------------------------------------------------------------------
// Kernel 0: W (64,768) fp32 -> Wt (768,64) bf16, 0.125*log2e folded for Q.
// ---------------------------------------------------------------------------
__global__ __launch_bounds__(256) void wt_kernel(
    const float* __restrict__ Wq, const float* __restrict__ Wk,
    const float* __restrict__ Wv, __bf16* __restrict__ Wt)
{
    __shared__ float tile[64][69];
    const int by = blockIdx.y;
    const float* W = by == 0 ? Wq : (by == 1 ? Wk : Wv);
    const float scale = (by == 0) ? 0.125f * LOG2E : 1.0f;
    const int p0 = blockIdx.x * 64;
    const int tl = threadIdx.x & 63;
    const int tq = threadIdx.x >> 6;
    #pragma unroll
    for (int i = 0; i < 16; ++i) {
        const int d = tq + 4 * i;
        tile[tl][d] = W[(size_t)d * NP + p0 + tl];
    }
    __syncthreads();
    #pragma unroll
    for (int i = 0; i < 16; ++i) {
        const int pl = tq + 4 * i;
        Wt[((size_t)by * NP + p0 + pl) * HD + tl] = (__bf16)(tile[pl][tl] * scale);
    }
}

// ---------------------------------------------------------------------------
// Kernel 1 v7: QKV projection. grid (128, 6); block = 64 t-rows, 4 waves;
// each (block, gi) does 6 of the 36 (proj,head) tiles. Q/K tiles (gi 0..3)
// are BARRIER-FREE: wave writes/reads only its own 16 rows of the LDS tile.
// V tiles (gi 4,5): block-coop transpose, wave = one 16-t chunk across all
// 64 d-rows (2-way LDS aliasing = free), 2 barriers per tile.
// ---------------------------------------------------------------------------
__global__ __launch_bounds__(256) void qkv_kernel(
    const float* __restrict__ hidden, const __bf16* __restrict__ Wt,
    const float* __restrict__ bq, const float* __restrict__ bk,
    const float* __restrict__ bv,
    __bf16* __restrict__ Qw, __bf16* __restrict__ Kw, __bf16* __restrict__ Vtw)
{
    __shared__ __bf16 ot[64][72];   // [t-local][d], 144B rows (16B aligned)

    const int tid  = threadIdx.x;
    const int lane = tid & 63;
    const int w    = tid >> 6;
    const int g    = lane >> 4;
    const int n    = lane & 15;

    const int row0 = blockIdx.x * 64;
    const int gi   = blockIdx.y;          // 0..5
    const int b_   = row0 >> 11;
    const int t0   = row0 & (SEQ - 1);

    // A fragments: wave w owns rows row0 + w*16 (+n)
    const float* hrow = hidden + (size_t)(row0 + w * 16 + n) * HD + 8 * g;
    f32x4 h0 = *(const f32x4*)(hrow);
    f32x4 h1 = *(const f32x4*)(hrow + 4);
    f32x4 h2 = *(const f32x4*)(hrow + 32);
    f32x4 h3 = *(const f32x4*)(hrow + 36);
    bf16x8 a0, a1;
    #pragma unroll
    for (int j = 0; j < 4; ++j) {
        a0[j]     = (__bf16)h0[j];
        a0[j + 4] = (__bf16)h1[j];
        a1[j]     = (__bf16)h2[j];
        a1[j + 4] = (__bf16)h3[j];
    }

    for (int tt = 0; tt < 6; ++tt) {
        const int tile_id = gi * 6 + tt;       // 0..35
        const int proj    = tile_id / 12;
        const int head    = tile_id % 12;
        const int bh      = b_ * NH + head;
        const float* bias = proj == 0 ? bq : (proj == 1 ? bk : bv);
        const float qs    = (proj == 0) ? 0.125f * LOG2E : 1.0f;
        const __bf16* Wp  = Wt + ((size_t)proj * NP + head * 64) * HD;

        bf16x8 w0[4], w1[4];
        #pragma unroll
        for (int dt = 0; dt < 4; ++dt) {
            const __bf16* wp = Wp + (size_t)(dt * 16 + n) * HD + 8 * g;
            w0[dt] = load_bf16x8(wp);
            w1[dt] = load_bf16x8(wp + 32);
        }
        #pragma unroll
        for (int dt = 0; dt < 4; ++dt) {
            f32x4 acc = {0.f, 0.f, 0.f, 0.f};
            acc = __builtin_amdgcn_mfma_f32_16x16x32_bf16(a0, w0[dt], acc, 0, 0, 0);
            acc = __builtin_amdgcn_mfma_f32_16x16x32_bf16(a1, w1[dt], acc, 0, 0, 0);
            const float bb = bias[head * 64 + dt * 16 + n] * qs;
            #pragma unroll
            for (int r = 0; r < 4; ++r)
                ot[w * 16 + 4 * g + r][dt * 16 + n] = (__bf16)(acc[r] + bb);
        }

        if (proj < 2) {
            // per-wave coalesced store of own 16 rows (no barrier)
            __bf16* dst = (proj ? Kw : Qw) + ((size_t)bh * SEQ + t0 + w * 16) * HD;
            const int tr = lane >> 2;
            const int d0 = (lane & 3) * 16;
            *(bf16x8*)(dst + (size_t)tr * HD + d0)     = *(const bf16x8*)&ot[w * 16 + tr][d0];
            *(bf16x8*)(dst + (size_t)tr * HD + d0 + 8) = *(const bf16x8*)&ot[w * 16 + tr][d0 + 8];
        } else {
            __syncthreads();   // all waves' C written
            // wave = one 16-t chunk, lanes = 64 d-rows: 2-way LDS alias only
            const int d  = lane;
            const int tc = w * 16;
            bf16x8 v0l, v1l;
            #pragma unroll
            for (int j = 0; j < 8; ++j) v0l[j] = ot[tc + j][d];
            #pragma unroll
            for (int j = 0; j < 8; ++j) v1l[j] = ot[tc + 8 + j][d];
            __bf16* vd = Vtw + ((size_t)bh * HD + d) * SEQ + t0 + tc;
            *(bf16x8*)vd       = v0l;
            *(bf16x8*)(vd + 8) = v1l;
            __syncthreads();   // reads done before next tile overwrites
        }
    }
}

// ---------------------------------------------------------------------------
// Kernel 2 v7: flash attention, 32x32x16 MFMAs, double-buffered LDS staging
// (one barrier/iter). Mask added to S^T via rank-1 MFMA (bf16 madd in LDS),
// row-sum l via MFMA with A=ones. Per 64-key iter: 10 S-side + 8 PV + 4 lsum
// MFMAs; VALU is just 32 exp2 + pack/exchange.
// ---------------------------------------------------------------------------
__global__ __launch_bounds__(256) void flash_attn_kernel(
    const __bf16* __restrict__ Qw, const __bf16* __restrict__ Kw,
    const __bf16* __restrict__ Vtw, const float* __restrict__ amask,
    float* __restrict__ out)
{
    __shared__ __align__(16) char smem[40960];
    __bf16 (*kt0)[72] = (__bf16(*)[72])(smem);
    __bf16 (*vt0)[72] = (__bf16(*)[72])(smem + 9216);
    __bf16 (*kt1)[72] = (__bf16(*)[72])(smem + 18432);
    __bf16 (*vt1)[72] = (__bf16(*)[72])(smem + 27648);
    __bf16* mdd       = (__bf16*)(smem + 36864);       // 2048 bf16
    float (*et)[32][68] = (float(*)[32][68])smem;      // epilogue alias

    const int tid  = threadIdx.x;
    const int lane = tid & 63;
    const int w    = tid >> 6;
    const int n32  = lane & 31;
    const int hi   = lane >> 5;

    const int bid    = blockIdx.x;        // 768
    const int xcd    = bid & 7;
    const int slot   = bid >> 3;          // 0..95
    const int bh     = xcd * 6 + (slot >> 4);
    const int qchunk = slot & 15;
    const int b_     = bh / NH;
    const int h      = bh % NH;
    const int q0     = qchunk * 128 + w * 32;

    // madd into LDS (bf16; mask==1 -> exactly 0)
    const float* mp = amask + (size_t)b_ * SEQ;
    for (int i = tid; i < SEQ; i += 256)
        mdd[i] = (__bf16)fmaf(mp[i], MASK_L2, -MASK_L2);

    // Q as B-operand: B[k=16*dstep+8*hi+j][q=n32]
    const __bf16* Qrow = Qw + ((size_t)bh * SEQ + q0 + n32) * HD + 8 * hi;
    bf16x8 qf[4];
    #pragma unroll
    for (int dstep = 0; dstep < 4; ++dstep)
        qf[dstep] = load_bf16x8(Qrow + dstep * 16);

    // constant fragments
    bf16x8 aones, qone;
    #pragma unroll
    for (int j = 0; j < 8; ++j) { aones[j] = (__bf16)1.0f; qone[j] = (__bf16)0.0f; }
    if (hi == 0) qone[0] = (__bf16)1.0f;   // B[k=0][q] = 1

    const __bf16* Kbh = Kw  + (size_t)bh * SEQ * HD;
    const __bf16* Vbh = Vtw + (size_t)bh * HD * SEQ;

    const int srow = tid >> 3;            // 0..31
    const int scol = (tid & 7) * 8;

    // stage tile 0 into buf0
    bf16x8 kreg[2], vreg[2];
    #pragma unroll
    for (int R = 0; R < 2; ++R) {
        kreg[R] = load_bf16x8(Kbh + (size_t)(R * 32 + srow) * HD + scol);
        vreg[R] = load_bf16x8(Vbh + (size_t)(R * 32 + srow) * SEQ + scol);
    }
    #pragma unroll
    for (int R = 0; R < 2; ++R) {
        *(bf16x8*)&kt0[R * 32 + srow][scol] = kreg[R];
        *(bf16x8*)&vt0[R * 32 + srow][scol] = vreg[R];
    }
    __syncthreads();   // also covers mdd init

    f32x16 o0   = {0,0,0,0,0,0,0,0,0,0,0,0,0,0,0,0};
    f32x16 o1   = {0,0,0,0,0,0,0,0,0,0,0,0,0,0,0,0};
    f32x16 lacc = {0,0,0,0,0,0,0,0,0,0,0,0,0,0,0,0};

    for (int kb = 0; kb < SEQ; kb += 64) {
        __bf16 (*kt)[72], (*vt)[72], (*nkt)[72], (*nvt)[72];
        if ((kb & 64) == 0) { kt = kt0; vt = vt0; nkt = kt1; nvt = vt1; }
        else                { kt = kt1; vt = vt1; nkt = kt0; nvt = vt0; }

        // prefetch next tile (consumed by ds_write at loop bottom)
        const int nkb = (kb + 64) & (SEQ - 1);
        #pragma unroll
        for (int R = 0; R < 2; ++R) {
            kreg[R] = load_bf16x8(Kbh + ((size_t)nkb + R * 32 + srow) * HD + scol);
            vreg[R] = load_bf16x8(Vbh + (size_t)(R * 32 + srow) * SEQ + nkb + scol);
        }

        // mask A-fragments (only k-slot 0 is live; B=qone zeroes the rest)
        bf16x8 maa, mab;
        #pragma unroll
        for (int j = 0; j < 8; ++j) { maa[j] = (__bf16)0.0f; mab[j] = (__bf16)0.0f; }
        maa[0] = mdd[kb + n32];
        mab[0] = mdd[kb + 32 + n32];

        // fragments from LDS
        bf16x8 kfa[4], kfb[4], vf0[4], vf1[4];
        #pragma unroll
        for (int dstep = 0; dstep < 4; ++dstep) {
            kfa[dstep] = *(const bf16x8*)&kt[n32][dstep * 16 + 8 * hi];
            kfb[dstep] = *(const bf16x8*)&kt[32 + n32][dstep * 16 + 8 * hi];
        }
        #pragma unroll
        for (int ks = 0; ks < 4; ++ks) {
            vf0[ks] = *(const bf16x8*)&vt[n32][ks * 16 + 8 * hi];
            vf1[ks] = *(const bf16x8*)&vt[32 + n32][ks * 16 + 8 * hi];
        }

        // S^T (log2 domain) + mask via rank-1 MFMA
        f32x16 sa = {0,0,0,0,0,0,0,0,0,0,0,0,0,0,0,0};
        f32x16 sb = {0,0,0,0,0,0,0,0,0,0,0,0,0,0,0,0};
        #pragma unroll
        for (int dstep = 0; dstep < 4; ++dstep) {
            sa = __builtin_amdgcn_mfma_f32_32x32x16_bf16(kfa[dstep], qf[dstep], sa, 0, 0, 0);
            sb = __builtin_amdgcn_mfma_f32_32x32x16_bf16(kfb[dstep], qf[dstep], sb, 0, 0, 0);
        }
        sa = __builtin_amdgcn_mfma_f32_32x32x16_bf16(maa, qone, sa, 0, 0, 0);
        sb = __builtin_amdgcn_mfma_f32_32x32x16_bf16(mab, qone, sb, 0, 0, 0);

        // exp2 + pack + half-wave exchange (v5/v6-verified indexing)
        bf16x8 pA0, pA1, pB0, pB1;
        #pragma unroll
        for (int half = 0; half < 2; ++half) {
            const f32x16& s = half ? sb : sa;
            float p[16];
            #pragma unroll
            for (int r = 0; r < 16; ++r) p[r] = hw_exp2(s[r]);
            unsigned pk[8], xp[8];
            #pragma unroll
            for (int i = 0; i < 8; ++i) pk[i] = pack_bf16(p[2 * i], p[2 * i + 1]);
            #pragma unroll
            for (int i = 0; i < 8; ++i) xp[i] = __shfl_xor(pk[i], 32);
            u32x4 B0, B1;
            B0[0] = hi ? xp[2] : pk[0];  B0[1] = hi ? xp[3] : pk[1];
            B0[2] = hi ? pk[2] : xp[0];  B0[3] = hi ? pk[3] : xp[1];
            B1[0] = hi ? xp[6] : pk[4];  B1[1] = hi ? xp[7] : pk[5];
            B1[2] = hi ? pk[6] : xp[4];  B1[3] = hi ? pk[7] : xp[5];
            if (half == 0) { pA0 = __builtin_bit_cast(bf16x8, B0); pA1 = __builtin_bit_cast(bf16x8, B1); }
            else           { pB0 = __builtin_bit_cast(bf16x8, B0); pB1 = __builtin_bit_cast(bf16x8, B1); }
        }

        // l via MFMA: every C row of (ones x P) equals the column sum
        lacc = __builtin_amdgcn_mfma_f32_32x32x16_bf16(aones, pA0, lacc, 0, 0, 0);
        lacc = __builtin_amdgcn_mfma_f32_32x32x16_bf16(aones, pA1, lacc, 0, 0, 0);
        lacc = __builtin_amdgcn_mfma_f32_32x32x16_bf16(aones, pB0, lacc, 0, 0, 0);
        lacc = __builtin_amdgcn_mfma_f32_32x32x16_bf16(aones, pB1, lacc, 0, 0, 0);

        o0 = __builtin_amdgcn_mfma_f32_32x32x16_bf16(vf0[0], pA0, o0, 0, 0, 0);
        o0 = __builtin_amdgcn_mfma_f32_32x32x16_bf16(vf0[1], pA1, o0, 0, 0, 0);
        o0 = __builtin_amdgcn_mfma_f32_32x32x16_bf16(vf0[2], pB0, o0, 0, 0, 0);
        o0 = __builtin_amdgcn_mfma_f32_32x32x16_bf16(vf0[3], pB1, o0, 0, 0, 0);
        o1 = __builtin_amdgcn_mfma_f32_32x32x16_bf16(vf1[0], pA0, o1, 0, 0, 0);
        o1 = __builtin_amdgcn_mfma_f32_32x32x16_bf16(vf1[1], pA1, o1, 0, 0, 0);
        o1 = __builtin_amdgcn_mfma_f32_32x32x16_bf16(vf1[2], pB0, o1, 0, 0, 0);
        o1 = __builtin_amdgcn_mfma_f32_32x32x16_bf16(vf1[3], pB1, o1, 0, 0, 0);

        // write prefetched tile into the other buffer; single barrier
        #pragma unroll
        for (int R = 0; R < 2; ++R) {
            *(bf16x8*)&nkt[R * 32 + srow][scol] = kreg[R];
            *(bf16x8*)&nvt[R * 32 + srow][scol] = vreg[R];
        }
        __syncthreads();
    }

    const float inv = 1.0f / lacc[0];

    // O^T -> O via LDS (aliases staging; all staging ops fenced by last barrier)
    #pragma unroll
    for (int r = 0; r < 16; ++r) {
        const int dl = (r & 3) + 8 * (r >> 2) + 4 * hi;
        et[w][n32][dl]      = o0[r] * inv;
        et[w][n32][32 + dl] = o1[r] * inv;
    }
    float* orow = out + ((size_t)(b_ * SEQ + q0 + n32)) * NP + h * HD + 32 * hi;
    #pragma unroll
    for (int j = 0; j < 8; ++j) {
        *(f32x4*)(orow + 4 * j) = *(const f32x4*)(&et[w][n32][32 * hi + 4 * j]);
    }
}

extern "C" void kernel_launch(void* const* d_in, const int* in_sizes, int n_in,
                              void* d_out, int out_size, void* d_ws, size_t ws_size,
                              hipStream_t stream) {
    const float* hidden = (const float*)d_in[0];
    const float* amask  = (const float*)d_in[1];
    const float* Wq     = (const float*)d_in[2];
    const float* bq     = (const float*)d_in[3];
    const float* Wk     = (const float*)d_in[4];
    const float* bk     = (const float*)d_in[5];
    const float* Wv     = (const float*)d_in[6];
    const float* bv     = (const float*)d_in[7];
    float* out = (float*)d_out;

    const size_t elems = (size_t)NB * NH * SEQ * HD; // 6,291,456
    __bf16* Qw  = (__bf16*)d_ws;
    __bf16* Kw  = Qw + elems;
    __bf16* Vtw = Kw + elems;
    __bf16* Wt  = Vtw + elems;   // 3*768*64 bf16

    wt_kernel<<<dim3(12, 3), 256, 0, stream>>>(Wq, Wk, Wv, Wt);

    qkv_kernel<<<dim3(128, 6), 256, 0, stream>>>(
        hidden, Wt, bq, bk, bv, Qw, Kw, Vtw);

    flash_attn_kernel<<<dim3(768), 256, 0, stream>>>(
        Qw, Kw, Vtw, amask, out);
}

// Round 9
// 177.412 us; speedup vs baseline: 3.5839x; 1.0724x over previous
//
#include <hip/hip_runtime.h>
#include <hip/hip_bf16.h>

#define NH 12
#define HD 64
#define NB 4
#define SEQ 2048
#define NP 768
#define LOG2E 1.44269504f
#define MASK_L2 14426.9504f   // 10000 * log2(e)

typedef __bf16 bf16x8 __attribute__((ext_vector_type(8)));
typedef float f32x4 __attribute__((ext_vector_type(4)));
typedef float f32x16 __attribute__((ext_vector_type(16)));
typedef unsigned u32x4 __attribute__((ext_vector_type(4)));

static __device__ __forceinline__ bf16x8 load_bf16x8(const __bf16* p) {
    return *reinterpret_cast<const bf16x8*>(p);
}
static __device__ __forceinline__ float hw_exp2(float x) {
    return __builtin_amdgcn_exp2f(x);
}
static __device__ __forceinline__ unsigned pack_bf16(float lo, float hi) {
    unsigned a = (unsigned)__builtin_bit_cast(unsigned short, (__bf16)lo);
    unsigned b = (unsigned)__builtin_bit_cast(unsigned short, (__bf16)hi);
    return a | (b << 16);
}

// ---------------------------------------------------------------------------
// Kernel 1 v8: QKV projection, W transpose fused (wt_kernel removed).
// grid (128, 6); block = 64 t-rows; each (block, gi) does 6 (proj,head) tiles.
// Per tile: W rows loaded coalesced fp32 -> written transposed+bf16 (+scale)
// into LDS -> contiguous 16B fragment reads. Outputs:
//   Q: row-major (bh, t, d)    [flash reads once per block]
//   Kf/Vf: PRE-FRAGMENTED per 64-key block: [bh][kb64][8 frags][64 lanes][8]
//   so flash A-operand loads are base + lane*16B (fully coalesced).
// ---------------------------------------------------------------------------
__global__ __launch_bounds__(256) void qkv_kernel(
    const float* __restrict__ hidden,
    const float* __restrict__ Wq, const float* __restrict__ Wk,
    const float* __restrict__ Wv,
    const float* __restrict__ bq, const float* __restrict__ bk,
    const float* __restrict__ bv,
    __bf16* __restrict__ Qw, __bf16* __restrict__ Kf, __bf16* __restrict__ Vf)
{
    __shared__ __bf16 wtileT[64][72];   // [c][k]  (B-frags read contiguous)
    __shared__ __bf16 ot[64][72];       // [t][c]

    const int tid  = threadIdx.x;
    const int lane = tid & 63;
    const int w    = tid >> 6;
    const int g    = lane >> 4;
    const int n    = lane & 15;
    const int n32  = lane & 31;
    const int hi   = lane >> 5;

    const int row0 = blockIdx.x * 64;
    const int gi   = blockIdx.y;          // 0..5
    const int b_   = row0 >> 11;
    const int t0   = row0 & (SEQ - 1);
    const int kb64 = t0 >> 6;

    // A fragments: wave w owns rows row0 + w*16 (+n)
    const float* hrow = hidden + (size_t)(row0 + w * 16 + n) * HD + 8 * g;
    f32x4 h0 = *(const f32x4*)(hrow);
    f32x4 h1 = *(const f32x4*)(hrow + 4);
    f32x4 h2 = *(const f32x4*)(hrow + 32);
    f32x4 h3 = *(const f32x4*)(hrow + 36);
    bf16x8 a0, a1;
    #pragma unroll
    for (int j = 0; j < 4; ++j) {
        a0[j]     = (__bf16)h0[j];
        a0[j + 4] = (__bf16)h1[j];
        a1[j]     = (__bf16)h2[j];
        a1[j + 4] = (__bf16)h3[j];
    }

    const int dr   = tid >> 2;        // 0..63 (W row = k)
    const int coff = (tid & 3) * 16;  // 16 consecutive cols

    for (int tt = 0; tt < 6; ++tt) {
        const int tile_id = gi * 6 + tt;       // 0..35
        const int proj    = tile_id / 12;
        const int head    = tile_id % 12;
        const int bh      = b_ * NH + head;
        const float* W    = proj == 0 ? Wq : (proj == 1 ? Wk : Wv);
        const float* bias = proj == 0 ? bq : (proj == 1 ? bk : bv);
        const float qs    = (proj == 0) ? 0.125f * LOG2E : 1.0f;

        // stage W tile transposed + scaled to bf16
        const float* wr = W + (size_t)dr * NP + head * 64 + coff;
        f32x4 x0 = *(const f32x4*)(wr);
        f32x4 x1 = *(const f32x4*)(wr + 4);
        f32x4 x2 = *(const f32x4*)(wr + 8);
        f32x4 x3 = *(const f32x4*)(wr + 12);
        #pragma unroll
        for (int i = 0; i < 4; ++i) {
            wtileT[coff + i     ][dr] = (__bf16)(x0[i] * qs);
            wtileT[coff + 4 + i ][dr] = (__bf16)(x1[i] * qs);
            wtileT[coff + 8 + i ][dr] = (__bf16)(x2[i] * qs);
            wtileT[coff + 12 + i][dr] = (__bf16)(x3[i] * qs);
        }
        __syncthreads();   // wtileT ready; also fences prev tile's ot reads

        #pragma unroll
        for (int dt = 0; dt < 4; ++dt) {
            const bf16x8 b0 = *(const bf16x8*)&wtileT[dt * 16 + n][8 * g];
            const bf16x8 b1 = *(const bf16x8*)&wtileT[dt * 16 + n][32 + 8 * g];
            f32x4 acc = {0.f, 0.f, 0.f, 0.f};
            acc = __builtin_amdgcn_mfma_f32_16x16x32_bf16(a0, b0, acc, 0, 0, 0);
            acc = __builtin_amdgcn_mfma_f32_16x16x32_bf16(a1, b1, acc, 0, 0, 0);
            const float bb = bias[head * 64 + dt * 16 + n] * qs;
            #pragma unroll
            for (int r = 0; r < 4; ++r)
                ot[w * 16 + 4 * g + r][dt * 16 + n] = (__bf16)(acc[r] + bb);
        }
        __syncthreads();   // ot complete; wtileT frag reads done

        if (proj == 0) {
            __bf16* dst = Qw + ((size_t)bh * SEQ + t0 + w * 16) * HD;
            const int tr = lane >> 2;
            const int d0 = (lane & 3) * 16;
            *(bf16x8*)(dst + (size_t)tr * HD + d0)     = *(const bf16x8*)&ot[w * 16 + tr][d0];
            *(bf16x8*)(dst + (size_t)tr * HD + d0 + 8) = *(const bf16x8*)&ot[w * 16 + tr][d0 + 8];
        } else if (proj == 1) {
            // Kf frag (dstep=w, sub): lane l = K[t0+sub*32+n32][w*16+8hi .. +8]
            __bf16* base = Kf + (size_t)bh * SEQ * HD + (size_t)kb64 * 4096;
            #pragma unroll
            for (int sub = 0; sub < 2; ++sub) {
                const bf16x8 fr = *(const bf16x8*)&ot[sub * 32 + n32][w * 16 + 8 * hi];
                *(bf16x8*)(base + (size_t)(w * 2 + sub) * 512 + lane * 8) = fr;
            }
        } else {
            // Vf frag (ks=w, dsub): lane l, elem j = V[t0+w*16+8hi+j][dsub*32+n32]
            __bf16* base = Vf + (size_t)bh * SEQ * HD + (size_t)kb64 * 4096;
            #pragma unroll
            for (int dsub = 0; dsub < 2; ++dsub) {
                bf16x8 v;
                #pragma unroll
                for (int j = 0; j < 8; ++j)
                    v[j] = ot[w * 16 + 8 * hi + j][dsub * 32 + n32];
                *(bf16x8*)(base + (size_t)(w * 2 + dsub) * 512 + lane * 8) = v;
            }
        }
    }
}

// ---------------------------------------------------------------------------
// Kernel 2 v8: flash attention, KEY-SPLIT waves — no barrier in the loop.
// Block = 32 q; wave w owns keys [w*512, w*512+512) in 8 x 64-key iters.
// All K/V fragment loads are coalesced 16B/lane from the pre-fragmented
// Kf/Vf layouts (L2-resident). Per iter: 8 S + 2 mask MFMAs, exp2 + scalar
// lsum, pack + half-wave exchange, 8 PV MFMAs. One __syncthreads total
// (before the cross-wave combine). grid = 48 bh x 64 q-chunks = 3072.
// ---------------------------------------------------------------------------
__global__ __launch_bounds__(256, 3) void flash_attn_kernel(
    const __bf16* __restrict__ Qw, const __bf16* __restrict__ Kf,
    const __bf16* __restrict__ Vf, const float* __restrict__ amask,
    float* __restrict__ out)
{
    __shared__ __align__(16) float et[4][32][68];   // per-wave O^T partials
    __shared__ float lrow[4][32];
    __shared__ __bf16 mdd[SEQ];

    const int tid  = threadIdx.x;
    const int lane = tid & 63;
    const int w    = tid >> 6;
    const int n32  = lane & 31;
    const int hi   = lane >> 5;

    const int bid    = blockIdx.x;        // 3072
    const int xcd    = bid & 7;
    const int slot   = bid >> 3;          // 0..383
    const int bh     = xcd * 6 + (slot >> 6);
    const int qchunk = slot & 63;
    const int b_     = bh / NH;
    const int h      = bh % NH;
    const int q0     = qchunk * 32;

    // per-wave mdd slice (same-wave RAW: no barrier needed)
    const float* mp = amask + (size_t)b_ * SEQ;
    #pragma unroll
    for (int i = 0; i < 8; ++i) {
        const int idx = w * 512 + i * 64 + lane;
        mdd[idx] = (__bf16)fmaf(mp[idx], MASK_L2, -MASK_L2);
    }

    // Q as B-operand: B[k=16*dstep+8*hi+j][q=n32]
    const __bf16* Qrow = Qw + ((size_t)bh * SEQ + q0 + n32) * HD + 8 * hi;
    bf16x8 qf[4];
    #pragma unroll
    for (int d = 0; d < 4; ++d) qf[d] = load_bf16x8(Qrow + d * 16);

    bf16x8 qone;
    #pragma unroll
    for (int j = 0; j < 8; ++j) qone[j] = (__bf16)0.0f;
    if (hi == 0) qone[0] = (__bf16)1.0f;   // B[k=0][q] = 1

    const __bf16* kfb_ = Kf + (size_t)bh * SEQ * HD + (size_t)lane * 8;
    const __bf16* vfb_ = Vf + (size_t)bh * SEQ * HD + (size_t)lane * 8;

    f32x16 o0 = {0,0,0,0,0,0,0,0,0,0,0,0,0,0,0,0};
    f32x16 o1 = {0,0,0,0,0,0,0,0,0,0,0,0,0,0,0,0};
    float lsl = 0.f;

    const int kstart = w * 512;
    for (int it = 0; it < 8; ++it) {
        const int kb = kstart + it * 64;
        const size_t foff = (size_t)(kb >> 6) * 4096;

        bf16x8 kfa[4], kfb[4];
        #pragma unroll
        for (int d = 0; d < 4; ++d) {
            kfa[d] = load_bf16x8(kfb_ + foff + (size_t)(2 * d) * 512);
            kfb[d] = load_bf16x8(kfb_ + foff + (size_t)(2 * d + 1) * 512);
        }

        bf16x8 maa, mab;
        #pragma unroll
        for (int j = 0; j < 8; ++j) { maa[j] = (__bf16)0.0f; mab[j] = (__bf16)0.0f; }
        maa[0] = mdd[kb + n32];
        mab[0] = mdd[kb + 32 + n32];

        // S^T (log2 domain) + mask via rank-1 MFMA
        f32x16 sa = {0,0,0,0,0,0,0,0,0,0,0,0,0,0,0,0};
        f32x16 sb = {0,0,0,0,0,0,0,0,0,0,0,0,0,0,0,0};
        #pragma unroll
        for (int d = 0; d < 4; ++d) {
            sa = __builtin_amdgcn_mfma_f32_32x32x16_bf16(kfa[d], qf[d], sa, 0, 0, 0);
            sb = __builtin_amdgcn_mfma_f32_32x32x16_bf16(kfb[d], qf[d], sb, 0, 0, 0);
        }
        sa = __builtin_amdgcn_mfma_f32_32x32x16_bf16(maa, qone, sa, 0, 0, 0);
        sb = __builtin_amdgcn_mfma_f32_32x32x16_bf16(mab, qone, sb, 0, 0, 0);

        // V fragments (issued here; consumed after exp/pack)
        bf16x8 vf0[4], vf1[4];
        #pragma unroll
        for (int k = 0; k < 4; ++k) {
            vf0[k] = load_bf16x8(vfb_ + foff + (size_t)(2 * k) * 512);
            vf1[k] = load_bf16x8(vfb_ + foff + (size_t)(2 * k + 1) * 512);
        }

        // exp2 + scalar lsum + pack + half-wave exchange (v5/v6/v7-verified)
        bf16x8 pA0, pA1, pB0, pB1;
        #pragma unroll
        for (int half = 0; half < 2; ++half) {
            const f32x16& s = half ? sb : sa;
            float p[16];
            #pragma unroll
            for (int r = 0; r < 16; ++r) { p[r] = hw_exp2(s[r]); lsl += p[r]; }
            unsigned pk[8], xp[8];
            #pragma unroll
            for (int i = 0; i < 8; ++i) pk[i] = pack_bf16(p[2 * i], p[2 * i + 1]);
            #pragma unroll
            for (int i = 0; i < 8; ++i) xp[i] = __shfl_xor(pk[i], 32);
            u32x4 B0, B1;
            B0[0] = hi ? xp[2] : pk[0];  B0[1] = hi ? xp[3] : pk[1];
            B0[2] = hi ? pk[2] : xp[0];  B0[3] = hi ? pk[3] : xp[1];
            B1[0] = hi ? xp[6] : pk[4];  B1[1] = hi ? xp[7] : pk[5];
            B1[2] = hi ? pk[6] : xp[4];  B1[3] = hi ? pk[7] : xp[5];
            if (half == 0) { pA0 = __builtin_bit_cast(bf16x8, B0); pA1 = __builtin_bit_cast(bf16x8, B1); }
            else           { pB0 = __builtin_bit_cast(bf16x8, B0); pB1 = __builtin_bit_cast(bf16x8, B1); }
        }

        o0 = __builtin_amdgcn_mfma_f32_32x32x16_bf16(vf0[0], pA0, o0, 0, 0, 0);
        o0 = __builtin_amdgcn_mfma_f32_32x32x16_bf16(vf0[1], pA1, o0, 0, 0, 0);
        o0 = __builtin_amdgcn_mfma_f32_32x32x16_bf16(vf0[2], pB0, o0, 0, 0, 0);
        o0 = __builtin_amdgcn_mfma_f32_32x32x16_bf16(vf0[3], pB1, o0, 0, 0, 0);
        o1 = __builtin_amdgcn_mfma_f32_32x32x16_bf16(vf1[0], pA0, o1, 0, 0, 0);
        o1 = __builtin_amdgcn_mfma_f32_32x32x16_bf16(vf1[1], pA1, o1, 0, 0, 0);
        o1 = __builtin_amdgcn_mfma_f32_32x32x16_bf16(vf1[2], pB0, o1, 0, 0, 0);
        o1 = __builtin_amdgcn_mfma_f32_32x32x16_bf16(vf1[3], pB1, o1, 0, 0, 0);
    }

    // per-wave partial row sums: q=n32 lives on lanes n32 and n32+32
    const float rs = lsl + __shfl_xor(lsl, 32);

    // stage per-wave partials, then cross-wave combine
    #pragma unroll
    for (int r = 0; r < 16; ++r) {
        const int dl = (r & 3) + 8 * (r >> 2) + 4 * hi;
        et[w][n32][dl]      = o0[r];
        et[w][n32][32 + dl] = o1[r];
    }
    if (lane < 32) lrow[w][n32] = rs;
    __syncthreads();

    const int q  = tid >> 3;
    const int d0 = (tid & 7) * 8;
    const float linv = 1.0f / (lrow[0][q] + lrow[1][q] + lrow[2][q] + lrow[3][q]);
    f32x4 acc0 = {0,0,0,0}, acc1 = {0,0,0,0};
    #pragma unroll
    for (int ww = 0; ww < 4; ++ww) {
        acc0 += *(const f32x4*)&et[ww][q][d0];
        acc1 += *(const f32x4*)&et[ww][q][d0 + 4];
    }
    float* orow = out + ((size_t)(b_ * SEQ + q0 + q)) * NP + h * HD + d0;
    f32x4 r0, r1;
    #pragma unroll
    for (int i = 0; i < 4; ++i) { r0[i] = acc0[i] * linv; r1[i] = acc1[i] * linv; }
    *(f32x4*)(orow)     = r0;
    *(f32x4*)(orow + 4) = r1;
}

extern "C" void kernel_launch(void* const* d_in, const int* in_sizes, int n_in,
                              void* d_out, int out_size, void* d_ws, size_t ws_size,
                              hipStream_t stream) {
    const float* hidden = (const float*)d_in[0];
    const float* amask  = (const float*)d_in[1];
    const float* Wq     = (const float*)d_in[2];
    const float* bq     = (const float*)d_in[3];
    const float* Wk     = (const float*)d_in[4];
    const float* bk     = (const float*)d_in[5];
    const float* Wv     = (const float*)d_in[6];
    const float* bv     = (const float*)d_in[7];
    float* out = (float*)d_out;

    const size_t elems = (size_t)NB * NH * SEQ * HD; // 6,291,456
    __bf16* Qw = (__bf16*)d_ws;
    __bf16* Kf = Qw + elems;
    __bf16* Vf = Kf + elems;

    qkv_kernel<<<dim3(128, 6), 256, 0, stream>>>(
        hidden, Wq, Wk, Wv, bq, bk, bv, Qw, Kf, Vf);

    flash_attn_kernel<<<dim3(3072), 256, 0, stream>>>(
        Qw, Kf, Vf, amask, out);
}